// Round 20
// baseline (265.401 us; speedup 1.0000x reference)
//
#include <hip/hip_runtime.h>
#include <stdint.h>

// ---- dims ----
// B=8, L=27, T=256, D=1152, GS=3, G=9, DD=512, H=8, HD=64, NQ=1, OD=2048
// Output dtype: FLOAT32 (verified round 4).
//
// Round 20:
//   score_k : prefetch depth 2 (two register banks, static indexing) to
//             cover ~900cyc HBM latency (~400cyc/chunk was exposed at
//             depth 1); grid swapped to (4,216) so the 4 tq-tiles of one
//             bl are dispatch-adjacent (tight DRAM window).
//   va_sm_k : grid swapped to (3,216) so the 3 d-thirds of one bl
//             co-dispatch -> interleaved reads merge into full-row streams.
// All else verbatim r19. Algebra (verified r9-r19): scores = K·Qk (bk
// cancels in softmax); pooled = (attn·V)·Wv + bv. All f32.

// ---------------------------------------------------------------------------
// K1: qk_fused. grid (27,8,3) = (l,h,dc), block 256.  [verbatim r18/r19]
// ---------------------------------------------------------------------------
__global__ __launch_bounds__(256) void qk_fused(
    const float* __restrict__ query, const float* __restrict__ Wq,
    const float* __restrict__ bq, const float* __restrict__ Wk,
    float* __restrict__ Qk)
{
  const int l = blockIdx.x, g = l / 3;
  const int h = blockIdx.y;
  const int dc = blockIdx.z;          // 0..2 (384 d each)
  const int tid = threadIdx.x;

  __shared__ float qv[1152];
  __shared__ float part[4][64];
  __shared__ float Qps[64];

  for (int i = tid; i < 1152; i += 256) qv[i] = query[(size_t)l * 1152 + i];
  __syncthreads();

  {
    const int e = tid & 63;
    const int kq = tid >> 6;          // 0..3, 288 d' each
    const float* W = Wq + (size_t)g * 1152 * 512 + h * 64 + e;
    float a0 = 0.f, a1 = 0.f;
    const int d0 = kq * 288;
#pragma unroll 4
    for (int d = d0; d < d0 + 288; d += 2) {
      a0 += qv[d]     * W[(size_t)d * 512];
      a1 += qv[d + 1] * W[(size_t)(d + 1) * 512];
    }
    part[kq][e] = a0 + a1;
  }
  __syncthreads();
  if (tid < 64) {
    const float r = part[0][tid] + part[1][tid] + part[2][tid] + part[3][tid];
    Qps[tid] = (r + bq[g * 512 + h * 64 + tid]) * 0.125f;
  }
  __syncthreads();

  const float4* q4base = (const float4*)Qps;
#pragma unroll
  for (int it = 0; it < 6; it++) {
    const int slot = it * 256 + tid;  // 0..1535
    const int eg = slot & 3;
    const int d  = dc * 384 + (slot >> 2);
    const float4* q4 = q4base + eg * 4;
    const float4* w4 = (const float4*)(Wk + (size_t)g * 1152 * 512 + (size_t)d * 512 + h * 64 + eg * 16);
    float acc = 0.f;
#pragma unroll
    for (int e = 0; e < 4; e++) {
      const float4 a = q4[e], b = w4[e];
      acc += a.x * b.x + a.y * b.y + a.z * b.z + a.w * b.w;
    }
    acc += __shfl_xor(acc, 1, 64);
    acc += __shfl_xor(acc, 2, 64);
    if (eg == 0) Qk[((size_t)l * 1152 + d) * 8 + h] = acc;
  }
}

// ---------------------------------------------------------------------------
// K2: scores[bl][t][h] = sum_d K[bl,t,d] * Qk[l,d,h]
// grid (4,216) = (tq, bl), block 256 (4 waves). lane = token, wave = d-slice.
// r17 transposed-LDS structure + DEPTH-2 prefetch (banks A/B, static names).
// ---------------------------------------------------------------------------
#define SCORE_LOAD(KR, QR, DC)                                                \
  {                                                                           \
    _Pragma("unroll")                                                         \
    for (int it = 0; it < 6; it++) {                                          \
      const int flat = it * 256 + tid;                                        \
      const int row = flat / 24;                                              \
      const int col = flat % 24;                                              \
      KR[it] = *(const float4*)(Kbase + (size_t)row * 1152 + (DC) * 96 + col * 4); \
    }                                                                         \
    if (tid < 192) QR = ((const float4*)(Qbase + (size_t)(DC) * 96 * 8))[tid];\
  }

#define SCORE_STORE(KR, QR)                                                   \
  {                                                                           \
    _Pragma("unroll")                                                         \
    for (int it = 0; it < 6; it++) {                                          \
      const int flat = it * 256 + tid;                                        \
      const int row = flat / 24;                                              \
      const int col = flat % 24;                                              \
      Kt[(col * 4 + 0) * 65 + row] = KR[it].x;                                \
      Kt[(col * 4 + 1) * 65 + row] = KR[it].y;                                \
      Kt[(col * 4 + 2) * 65 + row] = KR[it].z;                                \
      Kt[(col * 4 + 3) * 65 + row] = KR[it].w;                                \
    }                                                                         \
    if (tid < 192) ((float4*)Qs)[tid] = QR;                                   \
  }

#define SCORE_COMPUTE()                                                       \
  {                                                                           \
    _Pragma("unroll 4")                                                       \
    for (int j = 0; j < 24; j++) {                                            \
      const int d = wid * 24 + j;                                             \
      const float kv = Kt[d * 65 + lane];                                     \
      const float4 qa = *(const float4*)&Qs[d * 8];                           \
      const float4 qb = *(const float4*)&Qs[d * 8 + 4];                       \
      sc[0] = fmaf(kv, qa.x, sc[0]); sc[1] = fmaf(kv, qa.y, sc[1]);           \
      sc[2] = fmaf(kv, qa.z, sc[2]); sc[3] = fmaf(kv, qa.w, sc[3]);           \
      sc[4] = fmaf(kv, qb.x, sc[4]); sc[5] = fmaf(kv, qb.y, sc[5]);           \
      sc[6] = fmaf(kv, qb.z, sc[6]); sc[7] = fmaf(kv, qb.w, sc[7]);           \
    }                                                                         \
  }

__global__ __launch_bounds__(256) void score_k(
    const float* __restrict__ K, const float* __restrict__ Qk,
    float* __restrict__ scores)
{
  const int tq = blockIdx.x;          // 0..3 (64-token tile) -- FASTEST
  const int bl = blockIdx.y;          // 0..215
  const int l = bl % 27;
  const int tid = threadIdx.x;
  const int lane = tid & 63;          // token within tile
  const int wid = tid >> 6;           // wave = d-slice (24 d of each 96)

  __shared__ __align__(16) float Kt[96 * 65];   // 24,960 B; reused for reduce
  __shared__ __align__(16) float Qs[96 * 8];    // 3,072 B

  const float* Kbase = K + ((size_t)bl * 256 + tq * 64) * 1152;
  const float* Qbase = Qk + (size_t)l * 1152 * 8;

  float4 kA[6], kB[6];
  float4 qA, qB;
  float sc[8] = {0.f, 0.f, 0.f, 0.f, 0.f, 0.f, 0.f, 0.f};

  SCORE_LOAD(kA, qA, 0);
  SCORE_LOAD(kB, qB, 1);

  for (int dc = 0; dc < 12; dc += 2) {
    // even chunk: bank A
    SCORE_STORE(kA, qA);
    __syncthreads();
    if (dc + 2 < 12) SCORE_LOAD(kA, qA, dc + 2);   // 2-deep: flies over 2 computes
    SCORE_COMPUTE();
    __syncthreads();
    // odd chunk: bank B
    SCORE_STORE(kB, qB);
    __syncthreads();
    if (dc + 3 < 12) SCORE_LOAD(kB, qB, dc + 3);
    SCORE_COMPUTE();
    __syncthreads();
  }

  // reduce 4 wave-partials per (t,h) via Kt overlay
  *(float4*)&Kt[(wid * 64 + lane) * 8    ] = make_float4(sc[0], sc[1], sc[2], sc[3]);
  *(float4*)&Kt[(wid * 64 + lane) * 8 + 4] = make_float4(sc[4], sc[5], sc[6], sc[7]);
  __syncthreads();
  for (int out = tid; out < 512; out += 256) {
    const int t = out >> 3, h = out & 7;
    const float s = (Kt[(0 * 64 + t) * 8 + h] + Kt[(1 * 64 + t) * 8 + h])
                  + (Kt[(2 * 64 + t) * 8 + h] + Kt[(3 * 64 + t) * 8 + h]);
    scores[((size_t)bl * 256 + tq * 64 + t) * 8 + h] = s;
  }
}

// ---------------------------------------------------------------------------
// K3: va_sm_k = softmax (in-block) + VA.  grid (3,216) = (dt, bl), blk 384.
// dt fastest -> the 3 d-thirds of one bl co-dispatch (full-row DRAM merge).
// Body verbatim r19 (unroll-16 t-loop).
// ---------------------------------------------------------------------------
__global__ __launch_bounds__(384) void va_sm_k(
    const float* __restrict__ V, const float* __restrict__ scores,
    float* __restrict__ VA)
{
  const int dt = blockIdx.x;          // 0..2 (d-third of 384) -- FASTEST
  const int bl = blockIdx.y;          // 0..215
  const int tid = threadIdx.x;
  const int d  = dt * 384 + tid;

  __shared__ __align__(16) float at[2048];   // attn[t][h], 8KB
  __shared__ float red[4][8], red2[4][8];

  const int wid = tid >> 6, lane = tid & 63;
  float sc[8], p[8];
  if (tid < 256) {
    const float* src = scores + ((size_t)bl * 256 + tid) * 8;
#pragma unroll
    for (int h = 0; h < 8; h++) sc[h] = src[h];
#pragma unroll
    for (int h = 0; h < 8; h++) {
      float m = sc[h];
#pragma unroll
      for (int o = 1; o < 64; o <<= 1) m = fmaxf(m, __shfl_xor(m, o, 64));
      if (lane == 0) red[wid][h] = m;
    }
  }
  __syncthreads();
  if (tid < 256) {
#pragma unroll
    for (int h = 0; h < 8; h++) {
      const float M = fmaxf(fmaxf(red[0][h], red[1][h]), fmaxf(red[2][h], red[3][h]));
      p[h] = __expf(sc[h] - M);
      float s = p[h];
#pragma unroll
      for (int o = 1; o < 64; o <<= 1) s += __shfl_xor(s, o, 64);
      if (lane == 0) red2[wid][h] = s;
    }
  }
  __syncthreads();
  if (tid < 256) {
#pragma unroll
    for (int h = 0; h < 8; h++) {
      const float S = red2[0][h] + red2[1][h] + red2[2][h] + red2[3][h];
      at[tid * 8 + h] = p[h] * (1.0f / S);
    }
  }
  __syncthreads();

  // VA body: unroll 16 for memory-level parallelism
  const float* Vbase = V + (size_t)bl * 256 * 1152 + d;
  float acc[8] = {0.f, 0.f, 0.f, 0.f, 0.f, 0.f, 0.f, 0.f};
#pragma unroll 16
  for (int t = 0; t < 256; t++) {
    const float v = Vbase[(size_t)t * 1152];
    const float4 a0 = *(const float4*)&at[t * 8];      // broadcast
    const float4 a1 = *(const float4*)&at[t * 8 + 4];  // broadcast
    acc[0] = fmaf(a0.x, v, acc[0]); acc[1] = fmaf(a0.y, v, acc[1]);
    acc[2] = fmaf(a0.z, v, acc[2]); acc[3] = fmaf(a0.w, v, acc[3]);
    acc[4] = fmaf(a1.x, v, acc[4]); acc[5] = fmaf(a1.y, v, acc[5]);
    acc[6] = fmaf(a1.z, v, acc[6]); acc[7] = fmaf(a1.w, v, acc[7]);
  }
  float* dst = VA + (size_t)bl * 8 * 1152 + d;
#pragma unroll
  for (int h = 0; h < 8; h++) dst[(size_t)h * 1152] = acc[h];
}

// ---------------------------------------------------------------------------
// K4: psum[dz][bl][e*8+h] = sum_{d in quarter dz} VA[bl,h,d]*Wv[g,d,h*64+e]
// grid (27,8,4) = (l,h,dz); block 512.  [verbatim r19]
// ---------------------------------------------------------------------------
__global__ __launch_bounds__(512) void pv_mat(
    const float* __restrict__ VA, const float* __restrict__ Wv,
    float* __restrict__ psum)
{
  const int l = blockIdx.x, g = l / 3, h = blockIdx.y, dz = blockIdx.z;
  const int b = threadIdx.x >> 6, lane = threadIdx.x & 63;
  const int bl = b * 27 + l;
  const float* W = Wv + (size_t)g * 1152 * 512 + h * 64 + lane;
  const float* va = VA + ((size_t)bl * 8 + h) * 1152;   // wave-uniform
  const int d0 = dz * 288;
  float a0 = 0.f, a1 = 0.f, a2 = 0.f, a3 = 0.f;
#pragma unroll 2
  for (int d = d0; d < d0 + 288; d += 4) {
    a0 = fmaf(va[d],     W[(size_t)(d)     * 512], a0);
    a1 = fmaf(va[d + 1], W[(size_t)(d + 1) * 512], a1);
    a2 = fmaf(va[d + 2], W[(size_t)(d + 2) * 512], a2);
    a3 = fmaf(va[d + 3], W[(size_t)(d + 3) * 512], a3);
  }
  psum[((size_t)dz * 216 + bl) * 512 + lane * 8 + h] = (a0 + a1) + (a2 + a3);
}

// ---------------------------------------------------------------------------
// K5: out[bl,n] = pooled[bl,:]@Wo[g] + bo[g];  pooled = sum_dz psum + bv_perm
// grid (27,8), block 256.  [verbatim r19]
// ---------------------------------------------------------------------------
__global__ __launch_bounds__(256) void out_gemm(
    const float* __restrict__ psum, const float* __restrict__ bv,
    const float* __restrict__ Wo, const float* __restrict__ bo,
    float* __restrict__ out)
{
  const int l = blockIdx.x, g = l / 3;
  const int n = blockIdx.y * 256 + threadIdx.x;
  __shared__ float pl[8][512];
  for (int i = threadIdx.x; i < 4096; i += 256) {
    const int b = i >> 9, f = i & 511;
    const int bl = b * 27 + l;
    const int e = f >> 3, h = f & 7;           // f = e*8 + h
    float v = bv[g * 512 + h * 64 + e];
#pragma unroll
    for (int dz = 0; dz < 4; dz++)
      v += psum[((size_t)dz * 216 + bl) * 512 + f];
    pl[b][f] = v;
  }
  __syncthreads();
  const float* W = Wo + (size_t)g * 512 * 2048 + n;
  float acc[8] = {0.f, 0.f, 0.f, 0.f, 0.f, 0.f, 0.f, 0.f};
#pragma unroll 4
  for (int f = 0; f < 512; f++) {
    const float w = W[(size_t)f * 2048];
#pragma unroll
    for (int b = 0; b < 8; b++) acc[b] += pl[b][f] * w;
  }
  const float bb = bo[g * 2048 + n];
#pragma unroll
  for (int b = 0; b < 8; b++)
    out[(size_t)(b * 27 + l) * 2048 + n] = acc[b] + bb;
}

// ---------------------------------------------------------------------------
// sentinel: zero-fill f32 output (absmax would read ~1.06e-1 = max|ref|)
// ---------------------------------------------------------------------------
__global__ __launch_bounds__(256) void zfill(float* __restrict__ out, int n) {
  const int i = blockIdx.x * 256 + threadIdx.x;
  if (i < n) out[i] = 0.f;
}

// ---------------------------------------------------------------------------
extern "C" void kernel_launch(void* const* d_in, const int* in_sizes, int n_in,
                              void* d_out, int out_size, void* d_ws, size_t ws_size,
                              hipStream_t stream)
{
  float* out = (float*)d_out;   // f32 output (verified round 4)

  // ---- config guards ----
  bool ok = (n_in == 11) && (out_size == 8 * 27 * 2048);
  if (ok) {
    const int expect[11] = {
      8 * 27 * 256 * 1152,  // K
      8 * 27 * 256 * 1152,  // V
      27 * 1 * 1152,        // query
      9 * 1152 * 512,       // Wq
      9 * 512,              // bq
      9 * 1152 * 512,       // Wk
      9 * 512,              // bk
      9 * 1152 * 512,       // Wv
      9 * 512,              // bv
      9 * 512 * 2048,       // Wo
      9 * 2048              // bo
    };
    for (int i = 0; i < 11; i++) ok = ok && (in_sizes[i] == expect[i]);
  }
  const size_t NEED = 14321664;
  ok = ok && (ws_size >= NEED);

  if (!ok) {
    zfill<<<dim3((out_size + 255) / 256), dim3(256), 0, stream>>>(out, out_size);
    return;
  }

  const float* Kin   = (const float*)d_in[0];
  const float* Vin   = (const float*)d_in[1];
  const float* query = (const float*)d_in[2];
  const float* Wq    = (const float*)d_in[3];
  const float* bq    = (const float*)d_in[4];
  const float* Wk    = (const float*)d_in[5];
  const float* Wv    = (const float*)d_in[7];
  const float* bvp   = (const float*)d_in[8];
  const float* Wo    = (const float*)d_in[9];
  const float* bo    = (const float*)d_in[10];
  // bk (d_in[6]) unused: constant over t, cancels in softmax exactly.

  char* ws = (char*)d_ws;
  float* Qkw     = (float*)(ws + 55296);
  float* scoresw = (float*)(ws + 1050624);
  float* VAw     = (float*)(ws + 4589568);
  float* psumw   = (float*)(ws + 12552192);

  qk_fused<<<dim3(27, 8, 3), dim3(256), 0, stream>>>(query, Wq, bq, Wk, Qkw);
  score_k <<<dim3(4, 216),   dim3(256), 0, stream>>>(Kin, Qkw, scoresw);
  va_sm_k <<<dim3(3, 216),   dim3(384), 0, stream>>>(Vin, scoresw, VAw);
  pv_mat  <<<dim3(27, 8, 4), dim3(512), 0, stream>>>(VAw, Wv, psumw);
  out_gemm<<<dim3(27, 8),    dim3(256), 0, stream>>>(psumw, bvp, Wo, bo, out);
}